// Round 17
// baseline (83.159 us; speedup 1.0000x reference)
//
#include <hip/hip_runtime.h>
#include <hip/hip_bf16.h>

typedef __attribute__((ext_vector_type(4))) unsigned int uint4v;
typedef __attribute__((ext_vector_type(8))) short short8;
typedef __attribute__((ext_vector_type(16))) float floatx16;

#define NROWP 152
#define ROWB2 12288                      // 4 xi * 32 ch * 96B
#define BB2   ((size_t)NROWP*ROWB2)      // 1,867,776 B per batch per copy
#define COPYB ((size_t)8*BB2)            // 14,942,208 B per parity copy
#define STATS_OFF ((size_t)2*COPYB)      // 29,884,416
#define ABUF (38*2048)                   // staged A tile: 38 rows x 2KB
#define LDS_BYTES (2*ABUF)               // 155648, double-buffered

#define SB __builtin_amdgcn_sched_barrier(0)

__device__ __forceinline__ unsigned short f2b(float f){
  unsigned int u = __float_as_uint(f);
  return (unsigned short)((u + 0x7fffu + ((u >> 16) & 1u)) >> 16);  // RNE
}

__device__ __forceinline__ void gload_lds16(const void* g, void* l){
  __builtin_amdgcn_global_load_lds((const __attribute__((address_space(1))) unsigned int*)g,
                                   (__attribute__((address_space(3))) unsigned int*)l, 16, 0, 0);
}

// ---------------- Kernel 1: per-(b,c) mean/scale ----------------
__global__ __launch_bounds__(256) void k_stat(const float* __restrict__ x,
                                              float* __restrict__ stats){
  int bid = blockIdx.x;                  // = b*32 + c
  int t = threadIdx.x;
  const float* xc = x + ((size_t)bid << 14);
  float s = 0.f, ss = 0.f;
  #pragma unroll 4
  for (int k = 0; k < 64; ++k){
    float v = xc[t + (k << 8)];
    s += v; ss += v*v;
  }
  #pragma unroll
  for (int m = 32; m >= 1; m >>= 1){
    s  += __shfl_xor(s, m);
    ss += __shfl_xor(ss, m);
  }
  __shared__ float rs[4], rss[4];
  int wv = t >> 6, l = t & 63;
  if (l == 0){ rs[wv] = s; rss[wv] = ss; }
  __syncthreads();
  if (t == 0){
    float S  = rs[0]+rs[1]+rs[2]+rs[3];
    float SS = rss[0]+rss[1]+rss[2]+rss[3];
    float mean = S * (1.f/16384.f);
    float var  = (SS - S*mean) * (1.f/16383.f);   // ddof=1
    float sd = sqrtf(fmaxf(var, 0.f));
    stats[bid*2]   = mean;
    stats[bid*2+1] = (sd < 1e-9f) ? 0.f : 1.f/(sd*128.f);  // 1/(std*sqrt(16384))
  }
}

// ---------------- Kernel 2: standardize + overlapped-window pad ----------------
// pad[p][b][r][xi][ch][96B]: elem e of seg: xs_std[b][ch][(r-10)%128][(32xi+8seg+e+p)%128]
__global__ __launch_bounds__(512) void k_pack(const float* __restrict__ x,
                                              const float* __restrict__ stats,
                                              unsigned char* __restrict__ pad){
  __shared__ float rowbuf[32*129];       // +1 f32 pad per channel row
  int bid = blockIdx.x;
  int b = bid & 7, rg = bid >> 3;        // rg 0..37, rows 4rg..4rg+3
  int t = threadIdx.x;
  int ch = t >> 4, xq = t & 15;
  float mean  = stats[(b*32 + ch)*2];
  float scale = stats[(b*32 + ch)*2 + 1];
  const float* xc = x + ((size_t)(b*32 + ch) << 14);
  for (int rr = 0; rr < 4; ++rr){
    int r = rg*4 + rr;                   // 0..151
    int sy = (r + 118) & 127;            // (r-10) mod 128
    const float* src = xc + (sy << 7) + (xq << 3);
    float4 v0 = *(const float4*)src;
    float4 v1 = *(const float4*)(src + 4);
    float* rb = rowbuf + ch*129 + (xq << 3);
    rb[0] = (v0.x-mean)*scale; rb[1] = (v0.y-mean)*scale;
    rb[2] = (v0.z-mean)*scale; rb[3] = (v0.w-mean)*scale;
    rb[4] = (v1.x-mean)*scale; rb[5] = (v1.y-mean)*scale;
    rb[6] = (v1.z-mean)*scale; rb[7] = (v1.w-mean)*scale;
    __syncthreads();
    #pragma unroll
    for (int k = 0; k < 3; ++k){
      int u = t + (k << 9);              // 0..1535
      int pp = (u >= 768) ? 1 : 0;
      int u2 = u - 768*pp;
      int xi = u2 / 192;
      int u3 = u2 - 192*xi;
      int cq = u3 / 6;
      int seg = u3 - 6*cq;
      const float* rbq = rowbuf + cq*129;
      int x0 = 32*xi + 8*seg + pp;
      unsigned int d[4];
      #pragma unroll
      for (int e = 0; e < 4; ++e){
        unsigned int lo = f2b(rbq[(x0 + 2*e)     & 127]);
        unsigned int hi = f2b(rbq[(x0 + 2*e + 1) & 127]);
        d[e] = lo | (hi << 16);
      }
      uint4v ov = {d[0], d[1], d[2], d[3]};
      *(uint4v*)(pad + (size_t)pp*COPYB + ((size_t)(b*NROWP + r))*ROWB2
                 + (unsigned)(xi*3072 + cq*96 + seg*16)) = ov;
    }
    __syncthreads();
  }
}

// ---------------- Kernel 3: shifted Gram, 4-sub-phase interleave (T3+T4+T5) ----------------
// 256 blocks = (cg 0..31) x (b 0..7); 512 thr = 8 waves (kq 0..3 y-quarter, ks 0..1 K-half)
// Per tile: 4 phases of {ds_read ring / stage-DMA slice -> bar -> lgkm0 -> 14 MFMA -> B refills -> bar};
// single counted vmcnt(2) per tile (keeps newest 2 B loads in flight across the barrier).
__global__ __launch_bounds__(512, 1) void k_corr(const unsigned char* __restrict__ pad,
                                                 float* __restrict__ out){
  extern __shared__ char lds[];
  float* sf = (float*)lds;                // epilogue reuse

  int bid = blockIdx.x;
  int b = bid & 7, cg = bid >> 3;
  int dx, d0;
  if (cg < 2){ dx = 0; d0 = cg << 2; }                  // dy groups {0..6}, {4..10}
  else { int q = cg - 2; dx = 1 + q/3; d0 = -10 + 7*(q - 3*(q/3)); }
  int p = dx & 1, dxe = dx - p;           // parity copy + even residual shift

  int tid = threadIdx.x;
  int lane = tid & 63, wvi = tid >> 6;
  int ks = wvi & 1, kq = wvi >> 1;        // kq: 8-step y-quarter; ks: 16-x K-half
  unsigned offF = (unsigned)(ks*1024 + ((lane >> 5) << 9) + ((lane & 31) << 4));
  unsigned oA = (unsigned)((lane & 31)*96 + 2*dxe);
  unsigned oB = (unsigned)((lane & 31)*96 + 16*(2*ks + (lane >> 5)));

  const unsigned char* baseA = pad + (size_t)p*COPYB + (size_t)b*BB2;
  const unsigned char* baseB = pad + (size_t)b*BB2;     // copy 0, unshifted

  floatx16 acc[7];
  #pragma unroll
  for (int d = 0; d < 7; ++d) acc[d] = (floatx16)(0.0f);

  auto stageUnit = [&](int tt, char* buf, int s){
    int u = wvi + (s << 3);               // 76 units: rows 0..37 x cp 0..1
    if (u < 76){
      int row = u >> 1, cp = u & 1;
      int rab = 32*(tt >> 2) + 10 + d0;   // 0..147
      const unsigned char* g = baseA + (size_t)(rab + row)*ROWB2
            + (unsigned)((tt & 3)*3072) + oA + (unsigned)(16*(2*cp + (lane >> 5)));
      gload_lds16(g, buf + (unsigned)(row*2048 + cp*1024 + lane*16));
    }
  };
  auto pBrow = [&](int tt)->const unsigned char*{
    return baseB + (size_t)(32*(tt >> 2) + 10 + kq*8)*ROWB2
                 + (unsigned)((tt & 3)*3072) + oB;
  };

  // prologue: DMA tile 0, warm BQ rows 0..3 of tile 0
  #pragma unroll
  for (int s = 0; s < 10; ++s) stageUnit(0, lds, s);
  SB;
  short8 BQ[4];
  {
    const unsigned char* pB0 = pBrow(0);
    #pragma unroll
    for (int k = 0; k < 4; ++k) __builtin_memcpy(&BQ[k], pB0 + (size_t)k*ROWB2, 16);
  }
  SB;
  asm volatile("s_waitcnt vmcnt(4)" ::: "memory");      // stages done; 4 BQ in flight
  SB; __builtin_amdgcn_s_barrier(); SB;

  for (int t = 0; t < 16; ++t){
    const char* Ab = lds + (t&1)*ABUF + (kq*8)*2048 + offF;
    char* nbuf = lds + ((t+1)&1)*ABUF;
    const unsigned char* pBc = pBrow(t);
    const unsigned char* pBn = pBrow(t+1);
    bool more = (t < 15);
    short8 ring[8];
    auto STEP = [&](int yl){
      short8 bf = BQ[yl & 3];
      #pragma unroll
      for (int d = 0; d < 7; ++d)
        acc[d] = __builtin_amdgcn_mfma_f32_32x32x16_bf16(ring[(yl+d)&7], bf, acc[d], 0, 0, 0);
    };
    // ---------- phase 0: steps 0,1 ----------
    #pragma unroll
    for (int w = 0; w < 8; ++w) ring[w] = *(const short8*)(Ab + w*2048);
    if (more){ stageUnit(t+1,nbuf,0); stageUnit(t+1,nbuf,1); stageUnit(t+1,nbuf,2); }
    SB; __builtin_amdgcn_s_barrier();
    asm volatile("s_waitcnt lgkmcnt(0)" ::: "memory"); SB;
    __builtin_amdgcn_s_setprio(1); STEP(0); STEP(1); __builtin_amdgcn_s_setprio(0);
    __builtin_memcpy(&BQ[0], pBc + (size_t)4*ROWB2, 16);
    __builtin_memcpy(&BQ[1], pBc + (size_t)5*ROWB2, 16);
    SB; __builtin_amdgcn_s_barrier(); SB;
    // ---------- phase 1: steps 2,3 ----------
    ring[0] = *(const short8*)(Ab + 8*2048);
    ring[1] = *(const short8*)(Ab + 9*2048);
    if (more){ stageUnit(t+1,nbuf,3); stageUnit(t+1,nbuf,4); stageUnit(t+1,nbuf,5); }
    SB; __builtin_amdgcn_s_barrier();
    asm volatile("s_waitcnt lgkmcnt(0)" ::: "memory"); SB;
    __builtin_amdgcn_s_setprio(1); STEP(2); STEP(3); __builtin_amdgcn_s_setprio(0);
    __builtin_memcpy(&BQ[2], pBc + (size_t)6*ROWB2, 16);
    __builtin_memcpy(&BQ[3], pBc + (size_t)7*ROWB2, 16);
    SB; __builtin_amdgcn_s_barrier(); SB;
    // ---------- phase 2: steps 4,5 ----------
    ring[2] = *(const short8*)(Ab + 10*2048);
    ring[3] = *(const short8*)(Ab + 11*2048);
    if (more){ stageUnit(t+1,nbuf,6); stageUnit(t+1,nbuf,7); }
    SB; __builtin_amdgcn_s_barrier();
    asm volatile("s_waitcnt lgkmcnt(0)" ::: "memory"); SB;
    __builtin_amdgcn_s_setprio(1); STEP(4); STEP(5); __builtin_amdgcn_s_setprio(0);
    if (more){
      __builtin_memcpy(&BQ[0], pBn, 16);
      __builtin_memcpy(&BQ[1], pBn + (size_t)ROWB2, 16);
    }
    SB; __builtin_amdgcn_s_barrier(); SB;
    // ---------- phase 3: steps 6,7 ----------
    ring[4] = *(const short8*)(Ab + 12*2048);
    ring[5] = *(const short8*)(Ab + 13*2048);
    if (more){ stageUnit(t+1,nbuf,8); stageUnit(t+1,nbuf,9); }
    SB; __builtin_amdgcn_s_barrier();
    asm volatile("s_waitcnt lgkmcnt(0)" ::: "memory"); SB;
    __builtin_amdgcn_s_setprio(1); STEP(6); STEP(7); __builtin_amdgcn_s_setprio(0);
    if (more){
      __builtin_memcpy(&BQ[2], pBn + (size_t)2*ROWB2, 16);
      __builtin_memcpy(&BQ[3], pBn + (size_t)3*ROWB2, 16);
    }
    SB;
    if (more){ asm volatile("s_waitcnt vmcnt(2)" ::: "memory"); }  // own stages done
    SB; __builtin_amdgcn_s_barrier(); SB;
  }

  // ---- epilogue: 8-wave reduce per dy, triangle-routed stores ----
  int baseb = b * 232848;                 // 528*441
  #pragma unroll
  for (int d = 0; d < 7; ++d){
    #pragma unroll
    for (int r = 0; r < 16; ++r)
      sf[wvi*1024 + r*64 + lane] = acc[d][r];
    __syncthreads();
    int dy = d0 + d;
    #pragma unroll
    for (int k = 0; k < 2; ++k){
      int pp0 = tid + (k << 9);
      float v = 0.f;
      #pragma unroll
      for (int w = 0; w < 8; ++w) v += sf[w*1024 + pp0];
      int reg = pp0 >> 6, ln = pp0 & 63;
      int i = (reg & 3) + 8*(reg >> 2) + 4*(ln >> 5);   // C row (shifted operand channel)
      int j = ln & 31;                                   // C col
      if (i <= j){
        int pp = i*(65 - i)/2 + (j - i);
        out[baseb + pp*441 + (10+dy)*21 + (10+dx)] = v;
        if (i == j && (dy != 0 || dx != 0))
          out[baseb + pp*441 + (10-dy)*21 + (10-dx)] = v;   // autocorr symmetry
      } else {
        int pp = j*(65 - j)/2 + (i - j);
        out[baseb + pp*441 + (10-dy)*21 + (10-dx)] = v;     // pair (j,i) at (-dy,-dx)
      }
    }
    __syncthreads();
  }
}

extern "C" void kernel_launch(void* const* d_in, const int* in_sizes, int n_in,
                              void* d_out, int out_size, void* d_ws, size_t ws_size,
                              hipStream_t stream){
  const float* x = (const float*)d_in[0];
  unsigned char* pad = (unsigned char*)d_ws;             // 2 x 14.94 MB parity copies
  float* stats = (float*)((char*)d_ws + STATS_OFF);      // 256 x {mean, scale}
  float* out = (float*)d_out;
  hipFuncSetAttribute((const void*)k_corr, hipFuncAttributeMaxDynamicSharedMemorySize,
                      LDS_BYTES);
  k_stat<<<dim3(256), dim3(256), 0, stream>>>(x, stats);
  k_pack<<<dim3(304), dim3(512), 0, stream>>>(x, stats, pad);
  k_corr<<<dim3(256), dim3(512), LDS_BYTES, stream>>>(pad, out);
}

// Round 18
// 79.186 us; speedup vs baseline: 1.0502x; 1.0502x over previous
//
#include <hip/hip_runtime.h>
#include <hip/hip_bf16.h>

typedef __attribute__((ext_vector_type(4))) unsigned int uint4v;
typedef __attribute__((ext_vector_type(8))) short short8;
typedef __attribute__((ext_vector_type(16))) float floatx16;

#define NROWP 152
#define ROWB2 12288                      // 4 xi * 32 ch * 96B
#define BB2   ((size_t)NROWP*ROWB2)      // 1,867,776 B per batch per copy
#define COPYB ((size_t)8*BB2)            // 14,942,208 B per parity copy
#define PART_OFF ((size_t)2*COPYB)       // 29,884,416: 304 blocks x 32 ch x {S,SS}
#define STATS_OFF (PART_OFF + 304*32*2*4)
#define ABUF (38*2048)                   // staged A tile: 38 rows x 2KB
#define LDS_BYTES (2*ABUF)               // 155648, double-buffered

#define SB __builtin_amdgcn_sched_barrier(0)

__device__ __forceinline__ unsigned short f2b(float f){
  unsigned int u = __float_as_uint(f);
  return (unsigned short)((u + 0x7fffu + ((u >> 16) & 1u)) >> 16);  // RNE
}

__device__ __forceinline__ void gload_lds16(const void* g, void* l){
  __builtin_amdgcn_global_load_lds((const __attribute__((address_space(1))) unsigned int*)g,
                                   (__attribute__((address_space(3))) unsigned int*)l, 16, 0, 0);
}

// ---------------- Kernel 1: RAW pack (no stats dependency) + partial sums ----------------
// pad[p][b][r][xi][ch][96B]: elem e of seg: x_raw[b][ch][(r-10)%128][(32xi+8seg+e+p)%128] (bf16)
// part[bid][ch] = {Sx, Sxx} over rows r in [10,138) (each source row exactly once)
__global__ __launch_bounds__(512) void k_pack(const float* __restrict__ x,
                                              unsigned char* __restrict__ pad,
                                              float* __restrict__ part){
  __shared__ float rowbuf[32*129];       // +1 f32 pad per channel row
  int bid = blockIdx.x;
  int b = bid & 7, rg = bid >> 3;        // rg 0..37, rows 4rg..4rg+3
  int t = threadIdx.x;
  int ch = t >> 4, xq = t & 15;
  const float* xc = x + ((size_t)(b*32 + ch) << 14);
  float s = 0.f, ss = 0.f;
  for (int rr = 0; rr < 4; ++rr){
    int r = rg*4 + rr;                   // 0..151
    int sy = (r + 118) & 127;            // (r-10) mod 128
    const float* src = xc + (sy << 7) + (xq << 3);
    float4 v0 = *(const float4*)src;
    float4 v1 = *(const float4*)(src + 4);
    if (r >= 10 && r < 138){             // unique-coverage window
      s  += v0.x+v0.y+v0.z+v0.w + v1.x+v1.y+v1.z+v1.w;
      ss += v0.x*v0.x+v0.y*v0.y+v0.z*v0.z+v0.w*v0.w
          + v1.x*v1.x+v1.y*v1.y+v1.z*v1.z+v1.w*v1.w;
    }
    float* rb = rowbuf + ch*129 + (xq << 3);
    rb[0] = v0.x; rb[1] = v0.y; rb[2] = v0.z; rb[3] = v0.w;
    rb[4] = v1.x; rb[5] = v1.y; rb[6] = v1.z; rb[7] = v1.w;
    __syncthreads();
    #pragma unroll
    for (int k = 0; k < 3; ++k){
      int u = t + (k << 9);              // 0..1535
      int pp = (u >= 768) ? 1 : 0;
      int u2 = u - 768*pp;
      int xi = u2 / 192;
      int u3 = u2 - 192*xi;
      int cq = u3 / 6;
      int seg = u3 - 6*cq;
      const float* rbq = rowbuf + cq*129;
      int x0 = 32*xi + 8*seg + pp;
      unsigned int d[4];
      #pragma unroll
      for (int e = 0; e < 4; ++e){
        unsigned int lo = f2b(rbq[(x0 + 2*e)     & 127]);
        unsigned int hi = f2b(rbq[(x0 + 2*e + 1) & 127]);
        d[e] = lo | (hi << 16);
      }
      uint4v ov = {d[0], d[1], d[2], d[3]};
      *(uint4v*)(pad + (size_t)pp*COPYB + ((size_t)(b*NROWP + r))*ROWB2
                 + (unsigned)(xi*3072 + cq*96 + seg*16)) = ov;
    }
    __syncthreads();
  }
  // reduce over the 16 xq lanes of each channel (lanes ch*16..ch*16+15 are contiguous)
  #pragma unroll
  for (int m = 8; m >= 1; m >>= 1){
    s  += __shfl_xor(s, m);
    ss += __shfl_xor(ss, m);
  }
  if (xq == 0){
    part[(bid*32 + ch)*2]     = s;
    part[(bid*32 + ch)*2 + 1] = ss;
  }
}

// ---------------- Kernel 1b: deterministic stats fold (38 partials per (b,c)) ----------------
__global__ __launch_bounds__(256) void k_stat2(const float* __restrict__ part,
                                               float* __restrict__ stats){
  int t = threadIdx.x;                   // t = b*32 + c
  int b = t >> 5, c = t & 31;
  float S = 0.f, SS = 0.f;
  #pragma unroll
  for (int rg = 0; rg < 38; ++rg){
    int idx = (((rg << 3) + b)*32 + c)*2;
    S  += part[idx];
    SS += part[idx + 1];
  }
  float mean = S * (1.f/16384.f);
  float var  = (SS - S*mean) * (1.f/16383.f);   // ddof=1
  float sd = sqrtf(fmaxf(var, 0.f));
  stats[t*2]   = mean;
  stats[t*2+1] = (sd < 1e-9f) ? 0.f : 1.f/(sd*128.f);  // 1/(std*sqrt(16384))
}

// ---------------- Kernel 2: raw Gram via 32x32x16 MFMA (R16 schedule, unchanged) ----------------
// Epilogue applies cc = (G - n*mi*mj) * si*sj  (shift-invariant affine correction).
__global__ __launch_bounds__(512, 1) void k_corr(const unsigned char* __restrict__ pad,
                                                 const float* __restrict__ stats,
                                                 float* __restrict__ out){
  extern __shared__ char lds[];
  float* sf = (float*)lds;                // epilogue reuse

  int bid = blockIdx.x;
  int b = bid & 7, cg = bid >> 3;
  int dx, d0;
  if (cg < 2){ dx = 0; d0 = cg << 2; }                  // dy groups {0..6}, {4..10}
  else { int q = cg - 2; dx = 1 + q/3; d0 = -10 + 7*(q - 3*(q/3)); }
  int p = dx & 1, dxe = dx - p;           // parity copy + even residual shift

  int tid = threadIdx.x;
  int lane = tid & 63, wvi = tid >> 6;
  int ks = wvi & 1, kq = wvi >> 1;        // kq: 8-step y-quarter; ks: 16-x K-half
  unsigned offF = (unsigned)(ks*1024 + ((lane >> 5) << 9) + ((lane & 31) << 4));
  unsigned oA = (unsigned)((lane & 31)*96 + 2*dxe);
  unsigned oB = (unsigned)((lane & 31)*96 + 16*(2*ks + (lane >> 5)));

  const unsigned char* baseA = pad + (size_t)p*COPYB + (size_t)b*BB2;
  const unsigned char* baseB = pad + (size_t)b*BB2;     // copy 0, unshifted

  floatx16 acc[7];
  #pragma unroll
  for (int d = 0; d < 7; ++d) acc[d] = (floatx16)(0.0f);

  auto stageA = [&](int tt, char* buf){
    int rab = 32*(tt >> 2) + 10 + d0;     // 0..147
    unsigned xio = (unsigned)((tt & 3)*3072);
    #pragma unroll
    for (int s = 0; s < 10; ++s){
      int u = wvi + (s << 3);             // 76 units: rows 0..37 x cp 0..1
      if (s < 9 || wvi < 4){
        int row = u >> 1, cp = u & 1;
        const unsigned char* g = baseA + (size_t)(rab + row)*ROWB2 + xio
                                 + oA + (unsigned)(16*(2*cp + (lane >> 5)));
        gload_lds16(g, buf + (unsigned)(row*2048 + cp*1024 + lane*16));
      }
    }
  };
  auto pBrow = [&](int tt)->const unsigned char*{
    return baseB + (size_t)(32*(tt >> 2) + 10 + kq*8)*ROWB2
                 + (unsigned)((tt & 3)*3072) + oB;
  };

  // prologue: DMA tile 0, warm BQ rows 0..3 of tile 0
  stageA(0, lds);
  SB;
  short8 BQ[4];
  {
    const unsigned char* pB0 = pBrow(0);
    #pragma unroll
    for (int k = 0; k < 4; ++k) __builtin_memcpy(&BQ[k], pB0 + (size_t)k*ROWB2, 16);
  }
  SB;
  asm volatile("s_waitcnt vmcnt(4)" ::: "memory");      // DMA(0) done; BQ stays in flight
  SB; __builtin_amdgcn_s_barrier(); SB;

  for (int t = 0; t < 16; ++t){
    if (t < 15) stageA(t+1, lds + ((t+1)&1)*ABUF);      // oldest VMEM this tile
    SB;
    // ---- compute tile t ----
    const char* Ab = lds + (t&1)*ABUF + (kq*8)*2048 + offF;
    const unsigned char* pBc = pBrow(t);
    const unsigned char* pBn = pBrow(t+1);
    bool more = (t < 15);
    short8 ring[8];
    #pragma unroll
    for (int w = 0; w < 8; ++w) ring[w] = *(const short8*)(Ab + w*2048);
    __builtin_amdgcn_s_setprio(1);
    #pragma unroll
    for (int yl = 0; yl < 8; ++yl){
      short8 bf = BQ[yl & 3];
      #pragma unroll
      for (int d = 0; d < 7; ++d)
        acc[d] = __builtin_amdgcn_mfma_f32_32x32x16_bf16(ring[(yl+d)&7], bf, acc[d], 0, 0, 0);
      if (yl < 4)       __builtin_memcpy(&BQ[yl & 3], pBc + (size_t)(yl + 4)*ROWB2, 16);
      else if (more)    __builtin_memcpy(&BQ[yl & 3], pBn + (size_t)(yl - 4)*ROWB2, 16);
      if (yl < 6) ring[yl & 7] = *(const short8*)(Ab + (yl + 8)*2048);
    }
    __builtin_amdgcn_s_setprio(0);
    SB;
    asm volatile("s_waitcnt vmcnt(4) lgkmcnt(0)" ::: "memory");  // DMA(t+1) drained; 4 BQ live
    SB; __builtin_amdgcn_s_barrier(); SB;
  }

  // ---- epilogue: 8-wave reduce per dy, affine correction, triangle-routed stores ----
  int baseb = b * 232848;                 // 528*441
  const float* st = stats + b*64;         // {mean, scale} x 32 ch
  #pragma unroll
  for (int d = 0; d < 7; ++d){
    #pragma unroll
    for (int r = 0; r < 16; ++r)
      sf[wvi*1024 + r*64 + lane] = acc[d][r];
    __syncthreads();
    int dy = d0 + d;
    #pragma unroll
    for (int k = 0; k < 2; ++k){
      int pp0 = tid + (k << 9);
      float v0 = 0.f;
      #pragma unroll
      for (int w = 0; w < 8; ++w) v0 += sf[w*1024 + pp0];
      int reg = pp0 >> 6, ln = pp0 & 63;
      int i = (reg & 3) + 8*(reg >> 2) + 4*(ln >> 5);   // C row (shifted operand channel)
      int j = ln & 31;                                   // C col
      float mi = st[2*i], si = st[2*i+1];
      float mj = st[2*j], sj = st[2*j+1];
      float v = (v0 - 16384.f*mi*mj) * (si*sj);
      if (i <= j){
        int pp = i*(65 - i)/2 + (j - i);
        out[baseb + pp*441 + (10+dy)*21 + (10+dx)] = v;
        if (i == j && (dy != 0 || dx != 0))
          out[baseb + pp*441 + (10-dy)*21 + (10-dx)] = v;   // autocorr symmetry
      } else {
        int pp = j*(65 - j)/2 + (i - j);
        out[baseb + pp*441 + (10-dy)*21 + (10-dx)] = v;     // pair (j,i) at (-dy,-dx)
      }
    }
    __syncthreads();
  }
}

extern "C" void kernel_launch(void* const* d_in, const int* in_sizes, int n_in,
                              void* d_out, int out_size, void* d_ws, size_t ws_size,
                              hipStream_t stream){
  const float* x = (const float*)d_in[0];
  unsigned char* pad = (unsigned char*)d_ws;             // 2 x 14.94 MB parity copies
  float* part  = (float*)((char*)d_ws + PART_OFF);       // 304 x 32 x {S,SS}
  float* stats = (float*)((char*)d_ws + STATS_OFF);      // 256 x {mean, scale}
  float* out = (float*)d_out;
  hipFuncSetAttribute((const void*)k_corr, hipFuncAttributeMaxDynamicSharedMemorySize,
                      LDS_BYTES);
  k_pack<<<dim3(304), dim3(512), 0, stream>>>(x, pad, part);
  k_stat2<<<dim3(1), dim3(256), 0, stream>>>(part, stats);
  k_corr<<<dim3(256), dim3(512), LDS_BYTES, stream>>>(pad, stats, out);
}